// Round 7
// baseline (323.505 us; speedup 1.0000x reference)
//
#include <hip/hip_runtime.h>
#include <cstdint>
#include <cstddef>

#define N_NODES 50000
#define N_EDGES 800000
#define INC 128
#define HID 32
#define HEADS 8
#define OUTC 64
#define F1 (HEADS * HID) /* 256 */
#define NEG 0.2f

typedef unsigned short bf16_t;
typedef __attribute__((ext_vector_type(8))) short bf16x8;   // MFMA A/B frag (4 VGPR)
typedef __attribute__((ext_vector_type(4))) float f32x4;    // MFMA C/D frag

__device__ __forceinline__ float bf2f(bf16_t u) {
  union { unsigned int i; float f; } v;
  v.i = ((unsigned int)u) << 16;
  return v.f;
}
__device__ __forceinline__ bf16_t f2bf(float x) {
  union { float f; unsigned int u; } v;
  v.f = x;
  unsigned int r = v.u + 0x7FFFu + ((v.u >> 16) & 1u);  // RNE
  return (bf16_t)(r >> 16);
}
__device__ __forceinline__ float lrexp(float v) {
  return expf((v >= 0.f) ? v : NEG * v);
}

// ---------------------------------------------------------------------------
// Prep: W1/W2 transpose+convert to bf16, cnt zero-fill.
// ---------------------------------------------------------------------------
__global__ void prep_w(const float* __restrict__ W1, const float* __restrict__ W2,
                       bf16_t* __restrict__ W1t, bf16_t* __restrict__ W2t,
                       int* __restrict__ cnt) {
  int t = blockIdx.x * blockDim.x + threadIdx.x;
  if (t < N_NODES) cnt[t] = 0;
  if (t < F1 * INC) {
    int n = t / INC, k = t % INC;
    W1t[t] = f2bf(W1[(size_t)k * F1 + n]);
  } else {
    int u = t - F1 * INC;
    if (u < OUTC * F1) {
      int n = u / F1, k = u % F1;
      W2t[u] = f2bf(W2[(size_t)k * OUTC + n]);
    }
  }
}

// ---------------------------------------------------------------------------
// MFMA bf16 GEMM + fused alpha epilogue (unchanged from R6).
// ---------------------------------------------------------------------------
template <bool AF32, int HPT, int HTOT>
__global__ __launch_bounds__(256) void mfma_gemm_fused(
    const void* __restrict__ Av, const bf16_t* __restrict__ Bt,
    bf16_t* __restrict__ C, const float* __restrict__ a_src,
    const float* __restrict__ a_dst, float* __restrict__ as,
    float* __restrict__ ad, int M, int N, int K) {
  constexpr int BM = 64, BN = 64, BK = 64;
  __shared__ union SM {
    struct { bf16_t A[BM * BK]; bf16_t B[BN * BK]; } st;
    struct { float ct[64][65]; float pr[64][4]; } epi;
  } sm;

  const int tid = threadIdx.x;
  const int wave = tid >> 6, lane = tid & 63;
  const int wm = (wave >> 1) * 32, wn = (wave & 1) * 32;
  const int lr = lane & 15, lq = lane >> 4;
  const int m0 = blockIdx.y * BM, n0 = blockIdx.x * BN;
  const float* A32 = (const float*)Av;
  const bf16_t* A16 = (const bf16_t*)Av;

  f32x4 acc[2][2] = {};

  for (int k0 = 0; k0 < K; k0 += BK) {
#pragma unroll
    for (int p = 0; p < 2; p++) {
      int id = p * 256 + tid;
      int r = id >> 3, c = id & 7;
      int gm = m0 + r;
      uint4 v = make_uint4(0, 0, 0, 0);
      if constexpr (AF32) {
        if (gm < M) {
          const float4* ap =
              reinterpret_cast<const float4*>(&A32[(size_t)gm * K + k0 + c * 8]);
          float4 v0 = ap[0], v1 = ap[1];
          union { bf16_t h[8]; uint4 u; } pk;
          pk.h[0] = f2bf(v0.x); pk.h[1] = f2bf(v0.y);
          pk.h[2] = f2bf(v0.z); pk.h[3] = f2bf(v0.w);
          pk.h[4] = f2bf(v1.x); pk.h[5] = f2bf(v1.y);
          pk.h[6] = f2bf(v1.z); pk.h[7] = f2bf(v1.w);
          v = pk.u;
        }
      } else {
        if (gm < M) v = *reinterpret_cast<const uint4*>(&A16[(size_t)gm * K + k0 + c * 8]);
      }
      *reinterpret_cast<uint4*>(&sm.st.A[r * BK + ((c ^ (r & 7)) * 8)]) = v;
    }
#pragma unroll
    for (int p = 0; p < 2; p++) {
      int id = p * 256 + tid;
      int r = id >> 3, c = id & 7;
      uint4 v = *reinterpret_cast<const uint4*>(&Bt[(size_t)(n0 + r) * K + k0 + c * 8]);
      *reinterpret_cast<uint4*>(&sm.st.B[r * BK + ((c ^ (r & 7)) * 8)]) = v;
    }
    __syncthreads();
#pragma unroll
    for (int kk = 0; kk < 2; kk++) {
      bf16x8 af[2], bfr[2];
#pragma unroll
      for (int mi = 0; mi < 2; mi++) {
        int rr = wm + mi * 16 + lr;
        af[mi] = *reinterpret_cast<const bf16x8*>(
            &sm.st.A[rr * BK + (((kk * 4 + lq) ^ (rr & 7)) * 8)]);
      }
#pragma unroll
      for (int ni = 0; ni < 2; ni++) {
        int rr = wn + ni * 16 + lr;
        bfr[ni] = *reinterpret_cast<const bf16x8*>(
            &sm.st.B[rr * BK + (((kk * 4 + lq) ^ (rr & 7)) * 8)]);
      }
#pragma unroll
      for (int mi = 0; mi < 2; mi++)
#pragma unroll
        for (int ni = 0; ni < 2; ni++)
          acc[mi][ni] = __builtin_amdgcn_mfma_f32_16x16x32_bf16(
              af[mi], bfr[ni], acc[mi][ni], 0, 0, 0);
    }
    __syncthreads();
  }

  // stage C tile (fp32) to LDS for alpha dots
#pragma unroll
  for (int mi = 0; mi < 2; mi++)
#pragma unroll
    for (int ni = 0; ni < 2; ni++)
#pragma unroll
      for (int r = 0; r < 4; r++)
        sm.epi.ct[wm + mi * 16 + lq * 4 + r][wn + ni * 16 + lr] = acc[mi][ni][r];
  __syncthreads();

  // global C stores (bf16); C/D: col=lane&15, row=(lane>>4)*4+reg
#pragma unroll
  for (int mi = 0; mi < 2; mi++)
#pragma unroll
    for (int ni = 0; ni < 2; ni++)
#pragma unroll
      for (int r = 0; r < 4; r++) {
        int gm = m0 + wm + mi * 16 + lq * 4 + r;
        if (gm < M)
          C[(size_t)gm * N + n0 + wn + ni * 16 + lr] = f2bf(acc[mi][ni][r]);
      }

  // alpha: 64 rows x 4 parts; part&1 = column half, part&2 = src/dst
  {
    int row = tid >> 2, part = tid & 3;
    int gn = m0 + row;
    const float* av = ((part & 2) ? a_dst : a_src) + n0 + (part & 1) * 32;
    float dot = 0.f;
#pragma unroll
    for (int c = 0; c < 32; c++) dot += sm.epi.ct[row][(part & 1) * 32 + c] * av[c];
    if constexpr (HPT == 2) {
      if (gn < M) {
        float* tgt = (part & 2) ? ad : as;
        tgt[(size_t)gn * HTOT + (n0 >> 5) + (part & 1)] = dot;
      }
    } else {
      sm.epi.pr[row][part] = dot;
      __syncthreads();
      if (part == 0 && gn < M) {
        as[gn] = sm.epi.pr[row][0] + sm.epi.pr[row][1];
        ad[gn] = sm.epi.pr[row][2] + sm.epi.pr[row][3];
      }
    }
  }
}

// ---------------------------------------------------------------------------
// CSR build (unchanged from R6).
// ---------------------------------------------------------------------------
__global__ void deg_count(const int* __restrict__ dst, int* __restrict__ cnt) {
  int e = blockIdx.x * blockDim.x + threadIdx.x;
  if (e < N_EDGES) atomicAdd(&cnt[dst[e]], 1);
}

__global__ void partial_sum(const int* __restrict__ cnt, int* __restrict__ bsum) {
  __shared__ int s[256];
  int i = blockIdx.x * 256 + threadIdx.x;
  s[threadIdx.x] = (i < N_NODES) ? cnt[i] : 0;
  __syncthreads();
  for (int off = 128; off > 0; off >>= 1) {
    if (threadIdx.x < off) s[threadIdx.x] += s[threadIdx.x + off];
    __syncthreads();
  }
  if (threadIdx.x == 0) bsum[blockIdx.x] = s[0];
}

__global__ void block_scan(const int* __restrict__ cnt, const int* __restrict__ bsum,
                           int* __restrict__ rs, int nb) {
  __shared__ int s[256], sb[256];
  int t = threadIdx.x;
  sb[t] = (t < nb) ? bsum[t] : 0;
  __syncthreads();
  for (int off = 1; off < 256; off <<= 1) {
    int v = (t >= off) ? sb[t - off] : 0;
    __syncthreads();
    sb[t] += v;
    __syncthreads();
  }
  int base = (blockIdx.x > 0) ? sb[blockIdx.x - 1] : 0;
  int i = blockIdx.x * 256 + t;
  int v = (i < N_NODES) ? cnt[i] : 0;
  s[t] = v;
  __syncthreads();
  for (int off = 1; off < 256; off <<= 1) {
    int u = (t >= off) ? s[t - off] : 0;
    __syncthreads();
    s[t] += u;
    __syncthreads();
  }
  if (i < N_NODES) rs[i] = base + s[t] - v;  // exclusive
}

__global__ void fill_csr(const int* __restrict__ src, const int* __restrict__ dst,
                         const int* __restrict__ rs, int* __restrict__ cnt,
                         int* __restrict__ csr_src) {
  int e = blockIdx.x * blockDim.x + threadIdx.x;
  if (e >= N_EDGES) return;
  int d = dst[e];
  int pos = atomicSub(&cnt[d], 1) - 1;
  csr_src[rs[d] + pos] = src[e];
}

// ---------------------------------------------------------------------------
// Fused score+aggregate, layer 1. HALF-WAVE (32 lanes) per dst node: lane owns
// 8 consecutive feats (uint4 gather; 32 lanes cover the 512 B row). Per 4-edge
// chunk: 32 lanes score 4 edges x 8 heads, broadcast indices, issue 4 wide
// gathers back-to-back, then FMA. Padded edges carry w=0 (no tail branch).
// ---------------------------------------------------------------------------
__global__ __launch_bounds__(256) void gat_aggr1(
    const int* __restrict__ rs, const int* __restrict__ csr_src,
    const float* __restrict__ as, const float* __restrict__ ad,
    const bf16_t* __restrict__ hb, const float* __restrict__ bias,
    bf16_t* __restrict__ outp) {
  int d = blockIdx.x * 8 + (threadIdx.x >> 5);
  int sub = threadIdx.x & 31;
  if (d >= N_NODES) return;
  int beg = rs[d];
  int end = (d == N_NODES - 1) ? N_EDGES : rs[d + 1];
  const int sh = sub & 7;   // scorer head (lane scores edge slot sub>>3, head sh)
  const int es = sub >> 3;  // scorer edge slot 0..3
  const int ah = sub >> 2;  // aggregation head for feats 8*sub..8*sub+7
  float ad_h = ad[(size_t)d * 8 + sh];
  float acc[8] = {};
  float z = 0.f;

  for (int cb = beg; cb < end; cb += 4) {
    int ei = cb + es;
    int eidx = (ei < end) ? ei : end - 1;  // loop entered => end > beg >= 0
    int s_reg = csr_src[eidx];
    float w_reg = (ei < end) ? lrexp(as[(size_t)s_reg * 8 + sh] + ad_h) : 0.f;
    int sv[4];
#pragma unroll
    for (int e = 0; e < 4; e++) sv[e] = __shfl(s_reg, e << 3, 32);
    uint4 g[4];
#pragma unroll
    for (int e = 0; e < 4; e++)
      g[e] = *reinterpret_cast<const uint4*>(&hb[(size_t)sv[e] * F1 + 8 * sub]);
#pragma unroll
    for (int e = 0; e < 4; e++) {
      float wv = __shfl(w_reg, (e << 3) | ah, 32);
      union { uint4 u; bf16_t h[8]; } ld;
      ld.u = g[e];
#pragma unroll
      for (int q = 0; q < 8; q++) acc[q] += bf2f(ld.h[q]) * wv;
      z += wv;
    }
  }

  float inv = (end > beg) ? (1.f / z) : 0.f;
  union { bf16_t h[8]; uint4 u; } pk;
#pragma unroll
  for (int q = 0; q < 8; q++) {
    float v = acc[q] * inv + bias[8 * sub + q];
    pk.h[q] = f2bf((v > 0.f) ? v : expm1f(v));
  }
  *reinterpret_cast<uint4*>(&outp[(size_t)d * F1 + 8 * sub]) = pk.u;
}

// ---------------------------------------------------------------------------
// Fused score+aggregate, layer 2 (H=1, C=64). EIGHT lanes per dst node: lane
// owns 8 feats (uint4; 8 lanes cover the 128 B row), 8 nodes/wave. Per 8-edge
// chunk each lane scores one edge; one load inst per edge-slot serves all 8
// nodes in the wave.
// ---------------------------------------------------------------------------
__global__ __launch_bounds__(256) void gat_aggr2(
    const int* __restrict__ rs, const int* __restrict__ csr_src,
    const float* __restrict__ as, const float* __restrict__ ad,
    const bf16_t* __restrict__ hb, const float* __restrict__ bias,
    float* __restrict__ outp) {
  int d = blockIdx.x * 32 + (threadIdx.x >> 3);
  int sub = threadIdx.x & 7;
  if (d >= N_NODES) return;
  int beg = rs[d];
  int end = (d == N_NODES - 1) ? N_EDGES : rs[d + 1];
  float ad_d = ad[d];
  float acc[8] = {};
  float z = 0.f;

  for (int cb = beg; cb < end; cb += 8) {
    int ei = cb + sub;
    int eidx = (ei < end) ? ei : end - 1;
    int s_reg = csr_src[eidx];
    float w_reg = (ei < end) ? lrexp(as[s_reg] + ad_d) : 0.f;
    int sv[8];
#pragma unroll
    for (int e = 0; e < 8; e++) sv[e] = __shfl(s_reg, e, 8);
    uint4 g[8];
#pragma unroll
    for (int e = 0; e < 8; e++)
      g[e] = *reinterpret_cast<const uint4*>(&hb[(size_t)sv[e] * OUTC + 8 * sub]);
#pragma unroll
    for (int e = 0; e < 8; e++) {
      float wv = __shfl(w_reg, e, 8);
      union { uint4 u; bf16_t h[8]; } ld;
      ld.u = g[e];
#pragma unroll
      for (int q = 0; q < 8; q++) acc[q] += bf2f(ld.h[q]) * wv;
      z += wv;
    }
  }

  float inv = (end > beg) ? (1.f / z) : 0.f;
  float4 o0, o1;
  o0.x = acc[0] * inv + bias[8 * sub + 0];
  o0.y = acc[1] * inv + bias[8 * sub + 1];
  o0.z = acc[2] * inv + bias[8 * sub + 2];
  o0.w = acc[3] * inv + bias[8 * sub + 3];
  o1.x = acc[4] * inv + bias[8 * sub + 4];
  o1.y = acc[5] * inv + bias[8 * sub + 5];
  o1.z = acc[6] * inv + bias[8 * sub + 6];
  o1.w = acc[7] * inv + bias[8 * sub + 7];
  *reinterpret_cast<float4*>(&outp[(size_t)d * OUTC + 8 * sub]) = o0;
  *reinterpret_cast<float4*>(&outp[(size_t)d * OUTC + 8 * sub + 4]) = o1;
}

extern "C" void kernel_launch(void* const* d_in, const int* in_sizes, int n_in,
                              void* d_out, int out_size, void* d_ws, size_t ws_size,
                              hipStream_t stream) {
  const float* x      = (const float*)d_in[0];
  const int*   ei     = (const int*)d_in[1];
  const float* W1     = (const float*)d_in[2];
  const float* a1_src = (const float*)d_in[3];
  const float* a1_dst = (const float*)d_in[4];
  const float* b1     = (const float*)d_in[5];
  const float* W2     = (const float*)d_in[6];
  const float* a2_src = (const float*)d_in[7];
  const float* a2_dst = (const float*)d_in[8];
  const float* b2     = (const float*)d_in[9];

  const int* src = ei;
  const int* dst = ei + N_EDGES;
  float* out = (float*)d_out;

  char* base = (char*)d_ws;
  size_t off = 0;
  auto carve = [&](size_t bytes) {
    void* q = base + off;
    off += (bytes + 255) & ~size_t(255);
    return q;
  };
  bf16_t* h1b  = (bf16_t*)carve((size_t)N_NODES * F1 * 2);     // 25.6 MB
  bf16_t* o1b  = (bf16_t*)carve((size_t)N_NODES * F1 * 2);     // 25.6 MB
  bf16_t* h2b  = (bf16_t*)carve((size_t)N_NODES * OUTC * 2);   // 6.4 MB
  bf16_t* W1t  = (bf16_t*)carve((size_t)F1 * INC * 2);
  bf16_t* W2t  = (bf16_t*)carve((size_t)OUTC * F1 * 2);
  float* as1 = (float*)carve((size_t)N_NODES * HEADS * 4);
  float* ad1 = (float*)carve((size_t)N_NODES * HEADS * 4);
  float* as2 = (float*)carve((size_t)N_NODES * 4);
  float* ad2 = (float*)carve((size_t)N_NODES * 4);
  int* cnt = (int*)carve((size_t)N_NODES * 4);
  int* rs = (int*)carve((size_t)N_NODES * 4);
  int* bsum = (int*)carve(256 * 4);
  int* csr_src = (int*)carve((size_t)N_EDGES * 4);

  constexpr int NB_SCAN = (N_NODES + 255) / 256;  // 196

  // ---- prep (W transposes + cnt=0) ----
  prep_w<<<(N_NODES + 255) / 256, 256, 0, stream>>>(W1, W2, W1t, W2t, cnt);

  // ---- CSR build ----
  deg_count<<<(N_EDGES + 255) / 256, 256, 0, stream>>>(dst, cnt);
  partial_sum<<<NB_SCAN, 256, 0, stream>>>(cnt, bsum);
  block_scan<<<NB_SCAN, 256, 0, stream>>>(cnt, bsum, rs, NB_SCAN);
  fill_csr<<<(N_EDGES + 255) / 256, 256, 0, stream>>>(src, dst, rs, cnt, csr_src);

  // ---------------- layer 1 ----------------
  mfma_gemm_fused<true, 2, HEADS><<<dim3(F1 / 64, (N_NODES + 63) / 64), 256, 0, stream>>>(
      x, W1t, h1b, a1_src, a1_dst, as1, ad1, N_NODES, F1, INC);
  gat_aggr1<<<(N_NODES + 7) / 8, 256, 0, stream>>>(rs, csr_src, as1, ad1, h1b, b1, o1b);

  // ---------------- layer 2 ----------------
  mfma_gemm_fused<false, 1, 1><<<dim3(OUTC / 64, (N_NODES + 63) / 64), 256, 0, stream>>>(
      o1b, W2t, h2b, a2_src, a2_dst, as2, ad2, N_NODES, OUTC, F1);
  gat_aggr2<<<(N_NODES + 31) / 32, 256, 0, stream>>>(rs, csr_src, as2, ad2, h2b, b2, out);
}

// Round 8
// 311.320 us; speedup vs baseline: 1.0391x; 1.0391x over previous
//
#include <hip/hip_runtime.h>
#include <cstdint>
#include <cstddef>

#define N_NODES 50000
#define N_EDGES 800000
#define INC 128
#define HID 32
#define HEADS 8
#define OUTC 64
#define F1 (HEADS * HID) /* 256 */
#define NEG 0.2f

typedef unsigned short bf16_t;
typedef __attribute__((ext_vector_type(8))) short bf16x8;   // MFMA A/B frag (4 VGPR)
typedef __attribute__((ext_vector_type(4))) float f32x4;    // MFMA C/D frag

__device__ __forceinline__ float bf2f(bf16_t u) {
  union { unsigned int i; float f; } v;
  v.i = ((unsigned int)u) << 16;
  return v.f;
}
__device__ __forceinline__ bf16_t f2bf(float x) {
  union { float f; unsigned int u; } v;
  v.f = x;
  unsigned int r = v.u + 0x7FFFu + ((v.u >> 16) & 1u);  // RNE
  return (bf16_t)(r >> 16);
}
__device__ __forceinline__ float lrexp(float v) {
  return expf((v >= 0.f) ? v : NEG * v);
}

// ---------------------------------------------------------------------------
// Prep: W1/W2 transpose+convert to bf16, cnt zero-fill.
// ---------------------------------------------------------------------------
__global__ void prep_w(const float* __restrict__ W1, const float* __restrict__ W2,
                       bf16_t* __restrict__ W1t, bf16_t* __restrict__ W2t,
                       int* __restrict__ cnt) {
  int t = blockIdx.x * blockDim.x + threadIdx.x;
  if (t < N_NODES) cnt[t] = 0;
  if (t < F1 * INC) {
    int n = t / INC, k = t % INC;
    W1t[t] = f2bf(W1[(size_t)k * F1 + n]);
  } else {
    int u = t - F1 * INC;
    if (u < OUTC * F1) {
      int n = u / F1, k = u % F1;
      W2t[u] = f2bf(W2[(size_t)k * OUTC + n]);
    }
  }
}

// ---------------------------------------------------------------------------
// MFMA bf16 GEMM + fused alpha epilogue (unchanged from R6/R7).
// ---------------------------------------------------------------------------
template <bool AF32, int HPT, int HTOT>
__global__ __launch_bounds__(256) void mfma_gemm_fused(
    const void* __restrict__ Av, const bf16_t* __restrict__ Bt,
    bf16_t* __restrict__ C, const float* __restrict__ a_src,
    const float* __restrict__ a_dst, float* __restrict__ as,
    float* __restrict__ ad, int M, int N, int K) {
  constexpr int BM = 64, BN = 64, BK = 64;
  __shared__ union SM {
    struct { bf16_t A[BM * BK]; bf16_t B[BN * BK]; } st;
    struct { float ct[64][65]; float pr[64][4]; } epi;
  } sm;

  const int tid = threadIdx.x;
  const int wave = tid >> 6, lane = tid & 63;
  const int wm = (wave >> 1) * 32, wn = (wave & 1) * 32;
  const int lr = lane & 15, lq = lane >> 4;
  const int m0 = blockIdx.y * BM, n0 = blockIdx.x * BN;
  const float* A32 = (const float*)Av;
  const bf16_t* A16 = (const bf16_t*)Av;

  f32x4 acc[2][2] = {};

  for (int k0 = 0; k0 < K; k0 += BK) {
#pragma unroll
    for (int p = 0; p < 2; p++) {
      int id = p * 256 + tid;
      int r = id >> 3, c = id & 7;
      int gm = m0 + r;
      uint4 v = make_uint4(0, 0, 0, 0);
      if constexpr (AF32) {
        if (gm < M) {
          const float4* ap =
              reinterpret_cast<const float4*>(&A32[(size_t)gm * K + k0 + c * 8]);
          float4 v0 = ap[0], v1 = ap[1];
          union { bf16_t h[8]; uint4 u; } pk;
          pk.h[0] = f2bf(v0.x); pk.h[1] = f2bf(v0.y);
          pk.h[2] = f2bf(v0.z); pk.h[3] = f2bf(v0.w);
          pk.h[4] = f2bf(v1.x); pk.h[5] = f2bf(v1.y);
          pk.h[6] = f2bf(v1.z); pk.h[7] = f2bf(v1.w);
          v = pk.u;
        }
      } else {
        if (gm < M) v = *reinterpret_cast<const uint4*>(&A16[(size_t)gm * K + k0 + c * 8]);
      }
      *reinterpret_cast<uint4*>(&sm.st.A[r * BK + ((c ^ (r & 7)) * 8)]) = v;
    }
#pragma unroll
    for (int p = 0; p < 2; p++) {
      int id = p * 256 + tid;
      int r = id >> 3, c = id & 7;
      uint4 v = *reinterpret_cast<const uint4*>(&Bt[(size_t)(n0 + r) * K + k0 + c * 8]);
      *reinterpret_cast<uint4*>(&sm.st.B[r * BK + ((c ^ (r & 7)) * 8)]) = v;
    }
    __syncthreads();
#pragma unroll
    for (int kk = 0; kk < 2; kk++) {
      bf16x8 af[2], bfr[2];
#pragma unroll
      for (int mi = 0; mi < 2; mi++) {
        int rr = wm + mi * 16 + lr;
        af[mi] = *reinterpret_cast<const bf16x8*>(
            &sm.st.A[rr * BK + (((kk * 4 + lq) ^ (rr & 7)) * 8)]);
      }
#pragma unroll
      for (int ni = 0; ni < 2; ni++) {
        int rr = wn + ni * 16 + lr;
        bfr[ni] = *reinterpret_cast<const bf16x8*>(
            &sm.st.B[rr * BK + (((kk * 4 + lq) ^ (rr & 7)) * 8)]);
      }
#pragma unroll
      for (int mi = 0; mi < 2; mi++)
#pragma unroll
        for (int ni = 0; ni < 2; ni++)
          acc[mi][ni] = __builtin_amdgcn_mfma_f32_16x16x32_bf16(
              af[mi], bfr[ni], acc[mi][ni], 0, 0, 0);
    }
    __syncthreads();
  }

  // stage C tile (fp32) to LDS for alpha dots
#pragma unroll
  for (int mi = 0; mi < 2; mi++)
#pragma unroll
    for (int ni = 0; ni < 2; ni++)
#pragma unroll
      for (int r = 0; r < 4; r++)
        sm.epi.ct[wm + mi * 16 + lq * 4 + r][wn + ni * 16 + lr] = acc[mi][ni][r];
  __syncthreads();

  // global C stores (bf16); C/D: col=lane&15, row=(lane>>4)*4+reg
#pragma unroll
  for (int mi = 0; mi < 2; mi++)
#pragma unroll
    for (int ni = 0; ni < 2; ni++)
#pragma unroll
      for (int r = 0; r < 4; r++) {
        int gm = m0 + wm + mi * 16 + lq * 4 + r;
        if (gm < M)
          C[(size_t)gm * N + n0 + wn + ni * 16 + lr] = f2bf(acc[mi][ni][r]);
      }

  // alpha: 64 rows x 4 parts; part&1 = column half, part&2 = src/dst
  {
    int row = tid >> 2, part = tid & 3;
    int gn = m0 + row;
    const float* av = ((part & 2) ? a_dst : a_src) + n0 + (part & 1) * 32;
    float dot = 0.f;
#pragma unroll
    for (int c = 0; c < 32; c++) dot += sm.epi.ct[row][(part & 1) * 32 + c] * av[c];
    if constexpr (HPT == 2) {
      if (gn < M) {
        float* tgt = (part & 2) ? ad : as;
        tgt[(size_t)gn * HTOT + (n0 >> 5) + (part & 1)] = dot;
      }
    } else {
      sm.epi.pr[row][part] = dot;
      __syncthreads();
      if (part == 0 && gn < M) {
        as[gn] = sm.epi.pr[row][0] + sm.epi.pr[row][1];
        ad[gn] = sm.epi.pr[row][2] + sm.epi.pr[row][3];
      }
    }
  }
}

// ---------------------------------------------------------------------------
// CSR build (unchanged).
// ---------------------------------------------------------------------------
__global__ void deg_count(const int* __restrict__ dst, int* __restrict__ cnt) {
  int e = blockIdx.x * blockDim.x + threadIdx.x;
  if (e < N_EDGES) atomicAdd(&cnt[dst[e]], 1);
}

__global__ void partial_sum(const int* __restrict__ cnt, int* __restrict__ bsum) {
  __shared__ int s[256];
  int i = blockIdx.x * 256 + threadIdx.x;
  s[threadIdx.x] = (i < N_NODES) ? cnt[i] : 0;
  __syncthreads();
  for (int off = 128; off > 0; off >>= 1) {
    if (threadIdx.x < off) s[threadIdx.x] += s[threadIdx.x + off];
    __syncthreads();
  }
  if (threadIdx.x == 0) bsum[blockIdx.x] = s[0];
}

__global__ void block_scan(const int* __restrict__ cnt, const int* __restrict__ bsum,
                           int* __restrict__ rs, int nb) {
  __shared__ int s[256], sb[256];
  int t = threadIdx.x;
  sb[t] = (t < nb) ? bsum[t] : 0;
  __syncthreads();
  for (int off = 1; off < 256; off <<= 1) {
    int v = (t >= off) ? sb[t - off] : 0;
    __syncthreads();
    sb[t] += v;
    __syncthreads();
  }
  int base = (blockIdx.x > 0) ? sb[blockIdx.x - 1] : 0;
  int i = blockIdx.x * 256 + t;
  int v = (i < N_NODES) ? cnt[i] : 0;
  s[t] = v;
  __syncthreads();
  for (int off = 1; off < 256; off <<= 1) {
    int u = (t >= off) ? s[t - off] : 0;
    __syncthreads();
    s[t] += u;
    __syncthreads();
  }
  if (i < N_NODES) rs[i] = base + s[t] - v;  // exclusive
}

__global__ void fill_csr(const int* __restrict__ src, const int* __restrict__ dst,
                         const int* __restrict__ rs, int* __restrict__ cnt,
                         int* __restrict__ csr_src) {
  int e = blockIdx.x * blockDim.x + threadIdx.x;
  if (e >= N_EDGES) return;
  int d = dst[e];
  int pos = atomicSub(&cnt[d], 1) - 1;
  csr_src[rs[d] + pos] = src[e];
}

// ---------------------------------------------------------------------------
// Fused score+aggregate, layer 1. One full wave per dst node (R6 shape: best
// measured), lane owns 4 feats (uint2 gather), 8 edges/chunk. SOFTWARE
// PIPELINE: next chunk's csr_src load + score chain (as-gather + exp) overlap
// the current chunk's 8 in-flight h-gathers. Padded edges carry w=0.
// ---------------------------------------------------------------------------
__global__ __launch_bounds__(256) void gat_aggr1(
    const int* __restrict__ rs, const int* __restrict__ csr_src,
    const float* __restrict__ as, const float* __restrict__ ad,
    const bf16_t* __restrict__ hb, const float* __restrict__ bias,
    bf16_t* __restrict__ outp) {
  int d = blockIdx.x * 4 + (threadIdx.x >> 6);
  int lane = threadIdx.x & 63;
  if (d >= N_NODES) return;
  int beg = rs[d];
  int end = (d == N_NODES - 1) ? N_EDGES : rs[d + 1];
  const int sh = lane & 7;   // scorer head (lane scores edge lane>>3, head sh)
  const int ah = lane >> 3;  // aggregation head for feats 4*lane..4*lane+3
  float ad_h = ad[(size_t)d * 8 + sh];
  float a0 = 0.f, a1 = 0.f, a2 = 0.f, a3 = 0.f, z = 0.f;

  if (beg < end) {
    // prologue: chunk 0 indices + scores
    int ei = beg + (lane >> 3);
    int s_reg = csr_src[(ei < end) ? ei : end - 1];
    float w_reg = (ei < end) ? lrexp(as[(size_t)s_reg * 8 + sh] + ad_h) : 0.f;

    for (int cb = beg; cb < end; cb += 8) {
      // broadcast current chunk's indices, issue all 8 gathers
      int sv[8];
#pragma unroll
      for (int e = 0; e < 8; e++) sv[e] = __shfl(s_reg, e << 3);
      uint2 g[8];
#pragma unroll
      for (int e = 0; e < 8; e++)
        g[e] = *reinterpret_cast<const uint2*>(&hb[(size_t)sv[e] * F1 + 4 * lane]);
      float w_cur = w_reg;
      // prefetch next chunk's indices + scores while gathers are in flight
      int nxt = cb + 8;
      if (nxt < end) {
        int ei2 = nxt + (lane >> 3);
        s_reg = csr_src[(ei2 < end) ? ei2 : end - 1];
        w_reg = (ei2 < end) ? lrexp(as[(size_t)s_reg * 8 + sh] + ad_h) : 0.f;
      }
      // FMA current chunk
#pragma unroll
      for (int e = 0; e < 8; e++) {
        float wv = __shfl(w_cur, (e << 3) | ah);
        union { uint2 u; bf16_t h[4]; } ld;
        ld.u = g[e];
        a0 += bf2f(ld.h[0]) * wv;
        a1 += bf2f(ld.h[1]) * wv;
        a2 += bf2f(ld.h[2]) * wv;
        a3 += bf2f(ld.h[3]) * wv;
        z += wv;
      }
    }
  }

  float inv = (end > beg) ? (1.f / z) : 0.f;
  float v0 = a0 * inv + bias[4 * lane + 0];
  float v1 = a1 * inv + bias[4 * lane + 1];
  float v2 = a2 * inv + bias[4 * lane + 2];
  float v3 = a3 * inv + bias[4 * lane + 3];
  v0 = (v0 > 0.f) ? v0 : expm1f(v0);
  v1 = (v1 > 0.f) ? v1 : expm1f(v1);
  v2 = (v2 > 0.f) ? v2 : expm1f(v2);
  v3 = (v3 > 0.f) ? v3 : expm1f(v3);
  union { bf16_t h[4]; uint2 u; } pk;
  pk.h[0] = f2bf(v0); pk.h[1] = f2bf(v1); pk.h[2] = f2bf(v2); pk.h[3] = f2bf(v3);
  *reinterpret_cast<uint2*>(&outp[(size_t)d * F1 + 4 * lane]) = pk.u;
}

// ---------------------------------------------------------------------------
// Fused score+aggregate, layer 2 (H=1, C=64). Eight lanes per dst node (R7
// shape: measured win), lane owns 8 feats (uint4), 8 nodes/wave, 8 edges per
// chunk — now with the same score-prefetch pipeline.
// ---------------------------------------------------------------------------
__global__ __launch_bounds__(256) void gat_aggr2(
    const int* __restrict__ rs, const int* __restrict__ csr_src,
    const float* __restrict__ as, const float* __restrict__ ad,
    const bf16_t* __restrict__ hb, const float* __restrict__ bias,
    float* __restrict__ outp) {
  int d = blockIdx.x * 32 + (threadIdx.x >> 3);
  int sub = threadIdx.x & 7;
  if (d >= N_NODES) return;
  int beg = rs[d];
  int end = (d == N_NODES - 1) ? N_EDGES : rs[d + 1];
  float ad_d = ad[d];
  float acc[8] = {};
  float z = 0.f;

  if (beg < end) {
    int ei = beg + sub;
    int s_reg = csr_src[(ei < end) ? ei : end - 1];
    float w_reg = (ei < end) ? lrexp(as[s_reg] + ad_d) : 0.f;

    for (int cb = beg; cb < end; cb += 8) {
      int sv[8];
#pragma unroll
      for (int e = 0; e < 8; e++) sv[e] = __shfl(s_reg, e, 8);
      uint4 g[8];
#pragma unroll
      for (int e = 0; e < 8; e++)
        g[e] = *reinterpret_cast<const uint4*>(&hb[(size_t)sv[e] * OUTC + 8 * sub]);
      float w_cur = w_reg;
      int nxt = cb + 8;
      if (nxt < end) {
        int ei2 = nxt + sub;
        s_reg = csr_src[(ei2 < end) ? ei2 : end - 1];
        w_reg = (ei2 < end) ? lrexp(as[s_reg] + ad_d) : 0.f;
      }
#pragma unroll
      for (int e = 0; e < 8; e++) {
        float wv = __shfl(w_cur, e, 8);
        union { uint4 u; bf16_t h[8]; } ld;
        ld.u = g[e];
#pragma unroll
        for (int q = 0; q < 8; q++) acc[q] += bf2f(ld.h[q]) * wv;
        z += wv;
      }
    }
  }

  float inv = (end > beg) ? (1.f / z) : 0.f;
  float4 o0, o1;
  o0.x = acc[0] * inv + bias[8 * sub + 0];
  o0.y = acc[1] * inv + bias[8 * sub + 1];
  o0.z = acc[2] * inv + bias[8 * sub + 2];
  o0.w = acc[3] * inv + bias[8 * sub + 3];
  o1.x = acc[4] * inv + bias[8 * sub + 4];
  o1.y = acc[5] * inv + bias[8 * sub + 5];
  o1.z = acc[6] * inv + bias[8 * sub + 6];
  o1.w = acc[7] * inv + bias[8 * sub + 7];
  *reinterpret_cast<float4*>(&outp[(size_t)d * OUTC + 8 * sub]) = o0;
  *reinterpret_cast<float4*>(&outp[(size_t)d * OUTC + 8 * sub + 4]) = o1;
}

extern "C" void kernel_launch(void* const* d_in, const int* in_sizes, int n_in,
                              void* d_out, int out_size, void* d_ws, size_t ws_size,
                              hipStream_t stream) {
  const float* x      = (const float*)d_in[0];
  const int*   ei     = (const int*)d_in[1];
  const float* W1     = (const float*)d_in[2];
  const float* a1_src = (const float*)d_in[3];
  const float* a1_dst = (const float*)d_in[4];
  const float* b1     = (const float*)d_in[5];
  const float* W2     = (const float*)d_in[6];
  const float* a2_src = (const float*)d_in[7];
  const float* a2_dst = (const float*)d_in[8];
  const float* b2     = (const float*)d_in[9];

  const int* src = ei;
  const int* dst = ei + N_EDGES;
  float* out = (float*)d_out;

  char* base = (char*)d_ws;
  size_t off = 0;
  auto carve = [&](size_t bytes) {
    void* q = base + off;
    off += (bytes + 255) & ~size_t(255);
    return q;
  };
  bf16_t* h1b  = (bf16_t*)carve((size_t)N_NODES * F1 * 2);     // 25.6 MB
  bf16_t* o1b  = (bf16_t*)carve((size_t)N_NODES * F1 * 2);     // 25.6 MB
  bf16_t* h2b  = (bf16_t*)carve((size_t)N_NODES * OUTC * 2);   // 6.4 MB
  bf16_t* W1t  = (bf16_t*)carve((size_t)F1 * INC * 2);
  bf16_t* W2t  = (bf16_t*)carve((size_t)OUTC * F1 * 2);
  float* as1 = (float*)carve((size_t)N_NODES * HEADS * 4);
  float* ad1 = (float*)carve((size_t)N_NODES * HEADS * 4);
  float* as2 = (float*)carve((size_t)N_NODES * 4);
  float* ad2 = (float*)carve((size_t)N_NODES * 4);
  int* cnt = (int*)carve((size_t)N_NODES * 4);
  int* rs = (int*)carve((size_t)N_NODES * 4);
  int* bsum = (int*)carve(256 * 4);
  int* csr_src = (int*)carve((size_t)N_EDGES * 4);

  constexpr int NB_SCAN = (N_NODES + 255) / 256;  // 196

  // ---- prep (W transposes + cnt=0) ----
  prep_w<<<(N_NODES + 255) / 256, 256, 0, stream>>>(W1, W2, W1t, W2t, cnt);

  // ---- CSR build ----
  deg_count<<<(N_EDGES + 255) / 256, 256, 0, stream>>>(dst, cnt);
  partial_sum<<<NB_SCAN, 256, 0, stream>>>(cnt, bsum);
  block_scan<<<NB_SCAN, 256, 0, stream>>>(cnt, bsum, rs, NB_SCAN);
  fill_csr<<<(N_EDGES + 255) / 256, 256, 0, stream>>>(src, dst, rs, cnt, csr_src);

  // ---------------- layer 1 ----------------
  mfma_gemm_fused<true, 2, HEADS><<<dim3(F1 / 64, (N_NODES + 63) / 64), 256, 0, stream>>>(
      x, W1t, h1b, a1_src, a1_dst, as1, ad1, N_NODES, F1, INC);
  gat_aggr1<<<(N_NODES + 3) / 4, 256, 0, stream>>>(rs, csr_src, as1, ad1, h1b, b1, o1b);

  // ---------------- layer 2 ----------------
  mfma_gemm_fused<false, 1, 1><<<dim3(OUTC / 64, (N_NODES + 63) / 64), 256, 0, stream>>>(
      o1b, W2t, h2b, a2_src, a2_dst, as2, ad2, N_NODES, OUTC, F1);
  gat_aggr2<<<(N_NODES + 31) / 32, 256, 0, stream>>>(rs, csr_src, as2, ad2, h2b, b2, out);
}

// Round 9
// 291.640 us; speedup vs baseline: 1.1093x; 1.0675x over previous
//
#include <hip/hip_runtime.h>
#include <cstdint>
#include <cstddef>

#define N_NODES 50000
#define N_EDGES 800000
#define INC 128
#define HID 32
#define HEADS 8
#define OUTC 64
#define F1 (HEADS * HID) /* 256 */
#define NEG 0.2f

typedef unsigned short bf16_t;
typedef __attribute__((ext_vector_type(8))) short bf16x8;   // MFMA A/B frag (4 VGPR)
typedef __attribute__((ext_vector_type(4))) float f32x4;    // MFMA C/D frag

__device__ __forceinline__ float bf2f(bf16_t u) {
  union { unsigned int i; float f; } v;
  v.i = ((unsigned int)u) << 16;
  return v.f;
}
__device__ __forceinline__ bf16_t f2bf(float x) {
  union { float f; unsigned int u; } v;
  v.f = x;
  unsigned int r = v.u + 0x7FFFu + ((v.u >> 16) & 1u);  // RNE
  return (bf16_t)(r >> 16);
}
__device__ __forceinline__ float lrexp(float v) {
  return expf((v >= 0.f) ? v : NEG * v);
}

// ---------------------------------------------------------------------------
// Prep: W1/W2 transpose+convert to bf16. (cnt zeroing moved to memsetAsync.)
// ---------------------------------------------------------------------------
__global__ void prep_w(const float* __restrict__ W1, const float* __restrict__ W2,
                       bf16_t* __restrict__ W1t, bf16_t* __restrict__ W2t) {
  int t = blockIdx.x * blockDim.x + threadIdx.x;
  if (t < F1 * INC) {
    int n = t / INC, k = t % INC;
    W1t[t] = f2bf(W1[(size_t)k * F1 + n]);
  } else {
    int u = t - F1 * INC;
    if (u < OUTC * F1) {
      int n = u / F1, k = u % F1;
      W2t[u] = f2bf(W2[(size_t)k * OUTC + n]);
    }
  }
}

// ---------------------------------------------------------------------------
// MFMA bf16 GEMM + fused alpha epilogue + (layer1 only) fused edge histogram:
// the 800,768-thread grid exactly covers the 800k edges; the fire-and-forget
// atomicAdd hides under staging/MFMA (result unused -> no waitcnt).
// ---------------------------------------------------------------------------
template <bool AF32, int HPT, int HTOT>
__global__ __launch_bounds__(256) void mfma_gemm_fused(
    const void* __restrict__ Av, const bf16_t* __restrict__ Bt,
    bf16_t* __restrict__ C, const float* __restrict__ a_src,
    const float* __restrict__ a_dst, float* __restrict__ as,
    float* __restrict__ ad, int M, int N, int K,
    const int* __restrict__ dstE, int* __restrict__ cnt) {
  constexpr int BM = 64, BN = 64, BK = 64;
  __shared__ union SM {
    struct { bf16_t A[BM * BK]; bf16_t B[BN * BK]; } st;
    struct { float ct[64][65]; float pr[64][4]; } epi;
  } sm;

  const int tid = threadIdx.x;

  // fused deg_count (layer-1 instantiation only; cnt==nullptr for layer 2)
  if (cnt != nullptr) {
    int eid = (blockIdx.y * gridDim.x + blockIdx.x) * 256 + tid;
    if (eid < N_EDGES) atomicAdd(&cnt[dstE[eid]], 1);
  }

  const int wave = tid >> 6, lane = tid & 63;
  const int wm = (wave >> 1) * 32, wn = (wave & 1) * 32;
  const int lr = lane & 15, lq = lane >> 4;
  const int m0 = blockIdx.y * BM, n0 = blockIdx.x * BN;
  const float* A32 = (const float*)Av;
  const bf16_t* A16 = (const bf16_t*)Av;

  f32x4 acc[2][2] = {};

  for (int k0 = 0; k0 < K; k0 += BK) {
#pragma unroll
    for (int p = 0; p < 2; p++) {
      int id = p * 256 + tid;
      int r = id >> 3, c = id & 7;
      int gm = m0 + r;
      uint4 v = make_uint4(0, 0, 0, 0);
      if constexpr (AF32) {
        if (gm < M) {
          const float4* ap =
              reinterpret_cast<const float4*>(&A32[(size_t)gm * K + k0 + c * 8]);
          float4 v0 = ap[0], v1 = ap[1];
          union { bf16_t h[8]; uint4 u; } pk;
          pk.h[0] = f2bf(v0.x); pk.h[1] = f2bf(v0.y);
          pk.h[2] = f2bf(v0.z); pk.h[3] = f2bf(v0.w);
          pk.h[4] = f2bf(v1.x); pk.h[5] = f2bf(v1.y);
          pk.h[6] = f2bf(v1.z); pk.h[7] = f2bf(v1.w);
          v = pk.u;
        }
      } else {
        if (gm < M) v = *reinterpret_cast<const uint4*>(&A16[(size_t)gm * K + k0 + c * 8]);
      }
      *reinterpret_cast<uint4*>(&sm.st.A[r * BK + ((c ^ (r & 7)) * 8)]) = v;
    }
#pragma unroll
    for (int p = 0; p < 2; p++) {
      int id = p * 256 + tid;
      int r = id >> 3, c = id & 7;
      uint4 v = *reinterpret_cast<const uint4*>(&Bt[(size_t)(n0 + r) * K + k0 + c * 8]);
      *reinterpret_cast<uint4*>(&sm.st.B[r * BK + ((c ^ (r & 7)) * 8)]) = v;
    }
    __syncthreads();
#pragma unroll
    for (int kk = 0; kk < 2; kk++) {
      bf16x8 af[2], bfr[2];
#pragma unroll
      for (int mi = 0; mi < 2; mi++) {
        int rr = wm + mi * 16 + lr;
        af[mi] = *reinterpret_cast<const bf16x8*>(
            &sm.st.A[rr * BK + (((kk * 4 + lq) ^ (rr & 7)) * 8)]);
      }
#pragma unroll
      for (int ni = 0; ni < 2; ni++) {
        int rr = wn + ni * 16 + lr;
        bfr[ni] = *reinterpret_cast<const bf16x8*>(
            &sm.st.B[rr * BK + (((kk * 4 + lq) ^ (rr & 7)) * 8)]);
      }
#pragma unroll
      for (int mi = 0; mi < 2; mi++)
#pragma unroll
        for (int ni = 0; ni < 2; ni++)
          acc[mi][ni] = __builtin_amdgcn_mfma_f32_16x16x32_bf16(
              af[mi], bfr[ni], acc[mi][ni], 0, 0, 0);
    }
    __syncthreads();
  }

  // stage C tile (fp32) to LDS for alpha dots
#pragma unroll
  for (int mi = 0; mi < 2; mi++)
#pragma unroll
    for (int ni = 0; ni < 2; ni++)
#pragma unroll
      for (int r = 0; r < 4; r++)
        sm.epi.ct[wm + mi * 16 + lq * 4 + r][wn + ni * 16 + lr] = acc[mi][ni][r];
  __syncthreads();

  // global C stores (bf16); C/D: col=lane&15, row=(lane>>4)*4+reg
#pragma unroll
  for (int mi = 0; mi < 2; mi++)
#pragma unroll
    for (int ni = 0; ni < 2; ni++)
#pragma unroll
      for (int r = 0; r < 4; r++) {
        int gm = m0 + wm + mi * 16 + lq * 4 + r;
        if (gm < M)
          C[(size_t)gm * N + n0 + wn + ni * 16 + lr] = f2bf(acc[mi][ni][r]);
      }

  // alpha: 64 rows x 4 parts; part&1 = column half, part&2 = src/dst
  {
    int row = tid >> 2, part = tid & 3;
    int gn = m0 + row;
    const float* av = ((part & 2) ? a_dst : a_src) + n0 + (part & 1) * 32;
    float dot = 0.f;
#pragma unroll
    for (int c = 0; c < 32; c++) dot += sm.epi.ct[row][(part & 1) * 32 + c] * av[c];
    if constexpr (HPT == 2) {
      if (gn < M) {
        float* tgt = (part & 2) ? ad : as;
        tgt[(size_t)gn * HTOT + (n0 >> 5) + (part & 1)] = dot;
      }
    } else {
      sm.epi.pr[row][part] = dot;
      __syncthreads();
      if (part == 0 && gn < M) {
        as[gn] = sm.epi.pr[row][0] + sm.epi.pr[row][1];
        ad[gn] = sm.epi.pr[row][2] + sm.epi.pr[row][3];
      }
    }
  }
}

// ---------------------------------------------------------------------------
// CSR build (deg_count now fused into gemm1).
// ---------------------------------------------------------------------------
__global__ void partial_sum(const int* __restrict__ cnt, int* __restrict__ bsum) {
  __shared__ int s[256];
  int i = blockIdx.x * 256 + threadIdx.x;
  s[threadIdx.x] = (i < N_NODES) ? cnt[i] : 0;
  __syncthreads();
  for (int off = 128; off > 0; off >>= 1) {
    if (threadIdx.x < off) s[threadIdx.x] += s[threadIdx.x + off];
    __syncthreads();
  }
  if (threadIdx.x == 0) bsum[blockIdx.x] = s[0];
}

__global__ void block_scan(const int* __restrict__ cnt, const int* __restrict__ bsum,
                           int* __restrict__ rs, int nb) {
  __shared__ int s[256], sb[256];
  int t = threadIdx.x;
  sb[t] = (t < nb) ? bsum[t] : 0;
  __syncthreads();
  for (int off = 1; off < 256; off <<= 1) {
    int v = (t >= off) ? sb[t - off] : 0;
    __syncthreads();
    sb[t] += v;
    __syncthreads();
  }
  int base = (blockIdx.x > 0) ? sb[blockIdx.x - 1] : 0;
  int i = blockIdx.x * 256 + t;
  int v = (i < N_NODES) ? cnt[i] : 0;
  s[t] = v;
  __syncthreads();
  for (int off = 1; off < 256; off <<= 1) {
    int u = (t >= off) ? s[t - off] : 0;
    __syncthreads();
    s[t] += u;
    __syncthreads();
  }
  if (i < N_NODES) rs[i] = base + s[t] - v;  // exclusive
}

__global__ void fill_csr(const int* __restrict__ src, const int* __restrict__ dst,
                         const int* __restrict__ rs, int* __restrict__ cnt,
                         int* __restrict__ csr_src) {
  int e = blockIdx.x * blockDim.x + threadIdx.x;
  if (e >= N_EDGES) return;
  int d = dst[e];
  int pos = atomicSub(&cnt[d], 1) - 1;
  csr_src[rs[d] + pos] = src[e];
}

// ---------------------------------------------------------------------------
// Fused score+aggregate, layer 1. Wave per node, 8 edges/chunk, pipelined
// (R8 structure) + two instruction diets:
//  - readlane -> SGPR base pointers for the 8 h-gathers (saddr form: address
//    math on the scalar pipe; no index shuffles, no per-lane 64-bit adds)
//  - z accumulated in score layout (1 add/chunk), reduced once per node via
//    3x shfl_xor over the edge-slot bits.
// ---------------------------------------------------------------------------
__global__ __launch_bounds__(256) void gat_aggr1(
    const int* __restrict__ rs, const int* __restrict__ csr_src,
    const float* __restrict__ as, const float* __restrict__ ad,
    const bf16_t* __restrict__ hb, const float* __restrict__ bias,
    bf16_t* __restrict__ outp) {
  int d = blockIdx.x * 4 + (threadIdx.x >> 6);
  int lane = threadIdx.x & 63;
  if (d >= N_NODES) return;
  int beg = rs[d];
  int end = (d == N_NODES - 1) ? N_EDGES : rs[d + 1];
  const int sh = lane & 7;   // scorer head (lane scores edge slot lane>>3, head sh)
  const int ah = lane >> 3;  // aggregation head for feats 4*lane..4*lane+3
  float ad_h = ad[(size_t)d * 8 + sh];
  float a0 = 0.f, a1 = 0.f, a2 = 0.f, a3 = 0.f, zacc = 0.f;

  if (beg < end) {
    // prologue: chunk 0 indices + scores
    int ei = beg + (lane >> 3);
    int s_reg = csr_src[(ei < end) ? ei : end - 1];
    float w_reg = (ei < end) ? lrexp(as[(size_t)s_reg * 8 + sh] + ad_h) : 0.f;

    for (int cb = beg; cb < end; cb += 8) {
      // SGPR base pointers for current chunk's 8 gathers (wave-uniform)
      const bf16_t* bs[8];
#pragma unroll
      for (int e = 0; e < 8; e++)
        bs[e] = hb + (size_t)__builtin_amdgcn_readlane(s_reg, e << 3) * F1;
      uint2 g[8];
#pragma unroll
      for (int e = 0; e < 8; e++)
        g[e] = *reinterpret_cast<const uint2*>(bs[e] + 4 * lane);
      float w_cur = w_reg;
      zacc += w_reg;  // score-layout z: one add per chunk
      // prefetch next chunk's indices + scores while gathers are in flight
      int nxt = cb + 8;
      if (nxt < end) {
        int ei2 = nxt + (lane >> 3);
        s_reg = csr_src[(ei2 < end) ? ei2 : end - 1];
        w_reg = (ei2 < end) ? lrexp(as[(size_t)s_reg * 8 + sh] + ad_h) : 0.f;
      }
      // FMA current chunk
#pragma unroll
      for (int e = 0; e < 8; e++) {
        float wv = __shfl(w_cur, (e << 3) | ah);
        union { uint2 u; bf16_t h[4]; } ld;
        ld.u = g[e];
        a0 += bf2f(ld.h[0]) * wv;
        a1 += bf2f(ld.h[1]) * wv;
        a2 += bf2f(ld.h[2]) * wv;
        a3 += bf2f(ld.h[3]) * wv;
      }
    }
  }

  // z reduction over edge-slot bits (lane bits 3..5), then fetch for head ah
  float zr = zacc;
  zr += __shfl_xor(zr, 8);
  zr += __shfl_xor(zr, 16);
  zr += __shfl_xor(zr, 32);
  float z = __shfl(zr, ah);  // lane 'ah' holds (es=0, sh=ah)

  float inv = (end > beg) ? (1.f / z) : 0.f;
  float v0 = a0 * inv + bias[4 * lane + 0];
  float v1 = a1 * inv + bias[4 * lane + 1];
  float v2 = a2 * inv + bias[4 * lane + 2];
  float v3 = a3 * inv + bias[4 * lane + 3];
  v0 = (v0 > 0.f) ? v0 : expm1f(v0);
  v1 = (v1 > 0.f) ? v1 : expm1f(v1);
  v2 = (v2 > 0.f) ? v2 : expm1f(v2);
  v3 = (v3 > 0.f) ? v3 : expm1f(v3);
  union { bf16_t h[4]; uint2 u; } pk;
  pk.h[0] = f2bf(v0); pk.h[1] = f2bf(v1); pk.h[2] = f2bf(v2); pk.h[3] = f2bf(v3);
  *reinterpret_cast<uint2*>(&outp[(size_t)d * F1 + 4 * lane]) = pk.u;
}

// ---------------------------------------------------------------------------
// Fused score+aggregate, layer 2 (H=1, C=64). Eight lanes per dst node, lane
// owns 8 feats (uint4), 8 nodes/wave, pipelined; z via width-8 shfl_xor.
// (Indices NOT wave-uniform here -> keep __shfl broadcasts.)
// ---------------------------------------------------------------------------
__global__ __launch_bounds__(256) void gat_aggr2(
    const int* __restrict__ rs, const int* __restrict__ csr_src,
    const float* __restrict__ as, const float* __restrict__ ad,
    const bf16_t* __restrict__ hb, const float* __restrict__ bias,
    float* __restrict__ outp) {
  int d = blockIdx.x * 32 + (threadIdx.x >> 3);
  int sub = threadIdx.x & 7;
  if (d >= N_NODES) return;
  int beg = rs[d];
  int end = (d == N_NODES - 1) ? N_EDGES : rs[d + 1];
  float ad_d = ad[d];
  float acc[8] = {};
  float zacc = 0.f;

  if (beg < end) {
    int ei = beg + sub;
    int s_reg = csr_src[(ei < end) ? ei : end - 1];
    float w_reg = (ei < end) ? lrexp(as[s_reg] + ad_d) : 0.f;

    for (int cb = beg; cb < end; cb += 8) {
      int sv[8];
#pragma unroll
      for (int e = 0; e < 8; e++) sv[e] = __shfl(s_reg, e, 8);
      uint4 g[8];
#pragma unroll
      for (int e = 0; e < 8; e++)
        g[e] = *reinterpret_cast<const uint4*>(&hb[(size_t)sv[e] * OUTC + 8 * sub]);
      float w_cur = w_reg;
      zacc += w_reg;
      int nxt = cb + 8;
      if (nxt < end) {
        int ei2 = nxt + sub;
        s_reg = csr_src[(ei2 < end) ? ei2 : end - 1];
        w_reg = (ei2 < end) ? lrexp(as[s_reg] + ad_d) : 0.f;
      }
#pragma unroll
      for (int e = 0; e < 8; e++) {
        float wv = __shfl(w_cur, e, 8);
        union { uint4 u; bf16_t h[8]; } ld;
        ld.u = g[e];
#pragma unroll
        for (int q = 0; q < 8; q++) acc[q] += bf2f(ld.h[q]) * wv;
      }
    }
  }

  float zr = zacc;
  zr += __shfl_xor(zr, 1, 8);
  zr += __shfl_xor(zr, 2, 8);
  zr += __shfl_xor(zr, 4, 8);

  float inv = (end > beg) ? (1.f / zr) : 0.f;
  float4 o0, o1;
  o0.x = acc[0] * inv + bias[8 * sub + 0];
  o0.y = acc[1] * inv + bias[8 * sub + 1];
  o0.z = acc[2] * inv + bias[8 * sub + 2];
  o0.w = acc[3] * inv + bias[8 * sub + 3];
  o1.x = acc[4] * inv + bias[8 * sub + 4];
  o1.y = acc[5] * inv + bias[8 * sub + 5];
  o1.z = acc[6] * inv + bias[8 * sub + 6];
  o1.w = acc[7] * inv + bias[8 * sub + 7];
  *reinterpret_cast<float4*>(&outp[(size_t)d * OUTC + 8 * sub]) = o0;
  *reinterpret_cast<float4*>(&outp[(size_t)d * OUTC + 8 * sub + 4]) = o1;
}

extern "C" void kernel_launch(void* const* d_in, const int* in_sizes, int n_in,
                              void* d_out, int out_size, void* d_ws, size_t ws_size,
                              hipStream_t stream) {
  const float* x      = (const float*)d_in[0];
  const int*   ei     = (const int*)d_in[1];
  const float* W1     = (const float*)d_in[2];
  const float* a1_src = (const float*)d_in[3];
  const float* a1_dst = (const float*)d_in[4];
  const float* b1     = (const float*)d_in[5];
  const float* W2     = (const float*)d_in[6];
  const float* a2_src = (const float*)d_in[7];
  const float* a2_dst = (const float*)d_in[8];
  const float* b2     = (const float*)d_in[9];

  const int* src = ei;
  const int* dst = ei + N_EDGES;
  float* out = (float*)d_out;

  char* base = (char*)d_ws;
  size_t off = 0;
  auto carve = [&](size_t bytes) {
    void* q = base + off;
    off += (bytes + 255) & ~size_t(255);
    return q;
  };
  bf16_t* h1b  = (bf16_t*)carve((size_t)N_NODES * F1 * 2);     // 25.6 MB
  bf16_t* o1b  = (bf16_t*)carve((size_t)N_NODES * F1 * 2);     // 25.6 MB
  bf16_t* h2b  = (bf16_t*)carve((size_t)N_NODES * OUTC * 2);   // 6.4 MB
  bf16_t* W1t  = (bf16_t*)carve((size_t)F1 * INC * 2);
  bf16_t* W2t  = (bf16_t*)carve((size_t)OUTC * F1 * 2);
  float* as1 = (float*)carve((size_t)N_NODES * HEADS * 4);
  float* ad1 = (float*)carve((size_t)N_NODES * HEADS * 4);
  float* as2 = (float*)carve((size_t)N_NODES * 4);
  float* ad2 = (float*)carve((size_t)N_NODES * 4);
  int* cnt = (int*)carve((size_t)N_NODES * 4);
  int* rs = (int*)carve((size_t)N_NODES * 4);
  int* bsum = (int*)carve(256 * 4);
  int* csr_src = (int*)carve((size_t)N_EDGES * 4);

  constexpr int NB_SCAN = (N_NODES + 255) / 256;  // 196

  // cnt = 0 (deg histogram fused into gemm1 below)
  hipMemsetAsync(cnt, 0, N_NODES * sizeof(int), stream);

  // ---- prep (W transposes) ----
  prep_w<<<(F1 * INC + OUTC * F1 + 255) / 256, 256, 0, stream>>>(W1, W2, W1t, W2t);

  // ---------------- layer 1 GEMM (+ fused deg_count) ----------------
  mfma_gemm_fused<true, 2, HEADS><<<dim3(F1 / 64, (N_NODES + 63) / 64), 256, 0, stream>>>(
      x, W1t, h1b, a1_src, a1_dst, as1, ad1, N_NODES, F1, INC, dst, cnt);

  // ---- CSR build ----
  partial_sum<<<NB_SCAN, 256, 0, stream>>>(cnt, bsum);
  block_scan<<<NB_SCAN, 256, 0, stream>>>(cnt, bsum, rs, NB_SCAN);
  fill_csr<<<(N_EDGES + 255) / 256, 256, 0, stream>>>(src, dst, rs, cnt, csr_src);

  // ---------------- layer 1 aggregation ----------------
  gat_aggr1<<<(N_NODES + 3) / 4, 256, 0, stream>>>(rs, csr_src, as1, ad1, h1b, b1, o1b);

  // ---------------- layer 2 ----------------
  mfma_gemm_fused<false, 1, 1><<<dim3(OUTC / 64, (N_NODES + 63) / 64), 256, 0, stream>>>(
      o1b, W2t, h2b, a2_src, a2_dst, as2, ad2, N_NODES, OUTC, F1, nullptr, nullptr);
  gat_aggr2<<<(N_NODES + 31) / 32, 256, 0, stream>>>(rs, csr_src, as2, ad2, h2b, b2, out);
}